// Round 1
// baseline (133.687 us; speedup 1.0000x reference)
//
#include <hip/hip_runtime.h>
#include <hip/hip_bf16.h>
#include <math.h>

#define D_MODEL 512
#define D_LOW   64
#define NBINS   39
#define LOG2E   1.4426950408889634f
#define LN2     0.6931471805599453f

typedef __attribute__((ext_vector_type(8))) short short8;
typedef __attribute__((ext_vector_type(4))) float floatx4;

// ---------------------------------------------------------------------------
// Kernel 1 (lnproj_fused): one wave per block, grid = (BN/16) * 4.
// Block = 16 rows x 32 outs (out-group og = blockIdx & 3).
// The LN-affine weight fold (prev. prep kernel) is done INLINE: each wave
// re-derives its two folded bf16 weight columns, w2sum and b2 from the raw
// wu/wv/ln_w/ln_b. 96x redundant fold, but the kernel is latency-bound at
// 384 waves so the extra VALU is free; removes the w2bf round trip + 1 launch.
// ---------------------------------------------------------------------------
__global__ __launch_bounds__(64) void lnproj_fused_kernel(
    const float* __restrict__ h_res,
    const float* __restrict__ ln_w, const float* __restrict__ ln_b,
    const float* __restrict__ wu_w, const float* __restrict__ wu_b,
    const float* __restrict__ wv_w, const float* __restrict__ wv_b,
    float* __restrict__ U, __hip_bfloat16* __restrict__ Vbf, int N) {
  const int lane = threadIdx.x;
  const int q = lane >> 4, ln16 = lane & 15;
  const int rt = blockIdx.x >> 2, og = blockIdx.x & 3;
  const int row0 = rt * 16;
  const float* hp = h_res + (size_t)(row0 + ln16) * D_MODEL + q * 8;

  // --- load h rows, LN stats, bf16 A fragments ---
  short8 abf[16];
  float sum = 0.f, ssq = 0.f;
  #pragma unroll
  for (int kc = 0; kc < 16; ++kc) {
    const floatx4 x0 = *reinterpret_cast<const floatx4*>(hp + kc * 32);
    const floatx4 x1 = *reinterpret_cast<const floatx4*>(hp + kc * 32 + 4);
    short8 a;
    #pragma unroll
    for (int e = 0; e < 4; ++e) {
      sum += x0[e]; ssq += x0[e] * x0[e];
      const __hip_bfloat16 hb = __float2bfloat16(x0[e]);
      a[e] = *reinterpret_cast<const short*>(&hb);
    }
    #pragma unroll
    for (int e = 0; e < 4; ++e) {
      sum += x1[e]; ssq += x1[e] * x1[e];
      const __hip_bfloat16 hb = __float2bfloat16(x1[e]);
      a[4 + e] = *reinterpret_cast<const short*>(&hb);
    }
    abf[kc] = a;
  }
  sum += __shfl_xor(sum, 16); sum += __shfl_xor(sum, 32);
  ssq += __shfl_xor(ssq, 16); ssq += __shfl_xor(ssq, 32);
  const float mu  = sum * (1.0f / (float)D_MODEL);
  const float var = ssq * (1.0f / (float)D_MODEL) - mu * mu;
  const float rs  = rsqrtf(var + 1e-5f);
  float mu_r[4], rs_r[4];
  #pragma unroll
  for (int r = 0; r < 4; ++r) {
    mu_r[r] = __shfl(mu, q * 4 + r);
    rs_r[r] = __shfl(rs, q * 4 + r);
  }

  // --- inline fold + MFMA over K ---
  const int obase = og * 32;
  const int out0 = obase + ln16;
  const int out1 = obase + 16 + ln16;
  const bool isU = (og < 2);                 // og 0,1 -> U outs; og 2,3 -> V
  const float scale = isU ? LOG2E : 1.0f;
  const float* w0row = isU ? (wu_w + (size_t)out0 * D_MODEL)
                           : (wv_w + (size_t)(out0 - 64) * D_MODEL);
  const float* w1row = isU ? (wu_w + (size_t)out1 * D_MODEL)
                           : (wv_w + (size_t)(out1 - 64) * D_MODEL);

  floatx4 acc0 = (floatx4){0.f, 0.f, 0.f, 0.f};
  floatx4 acc1 = (floatx4){0.f, 0.f, 0.f, 0.f};
  float ws0 = 0.f, ws1 = 0.f, sb0 = 0.f, sb1 = 0.f;
  #pragma unroll
  for (int kc = 0; kc < 16; ++kc) {
    const int c0 = kc * 32 + q * 8;
    const floatx4 lw0 = *reinterpret_cast<const floatx4*>(ln_w + c0);
    const floatx4 lw1 = *reinterpret_cast<const floatx4*>(ln_w + c0 + 4);
    const floatx4 lb0 = *reinterpret_cast<const floatx4*>(ln_b + c0);
    const floatx4 lb1 = *reinterpret_cast<const floatx4*>(ln_b + c0 + 4);
    const floatx4 wa0 = *reinterpret_cast<const floatx4*>(w0row + c0);
    const floatx4 wa1 = *reinterpret_cast<const floatx4*>(w0row + c0 + 4);
    const floatx4 wc0 = *reinterpret_cast<const floatx4*>(w1row + c0);
    const floatx4 wc1 = *reinterpret_cast<const floatx4*>(w1row + c0 + 4);
    short8 b0, b1;
    #pragma unroll
    for (int e = 0; e < 4; ++e) {
      const float t0 = wa0[e] * lw0[e] * scale;
      const __hip_bfloat16 h0 = __float2bfloat16(t0);
      b0[e] = *reinterpret_cast<const short*>(&h0);
      ws0 += __bfloat162float(h0);
      sb0 += wa0[e] * lb0[e];

      const float t1 = wa1[e] * lw1[e] * scale;
      const __hip_bfloat16 h1 = __float2bfloat16(t1);
      b0[4 + e] = *reinterpret_cast<const short*>(&h1);
      ws0 += __bfloat162float(h1);
      sb0 += wa1[e] * lb1[e];

      const float t2 = wc0[e] * lw0[e] * scale;
      const __hip_bfloat16 h2 = __float2bfloat16(t2);
      b1[e] = *reinterpret_cast<const short*>(&h2);
      ws1 += __bfloat162float(h2);
      sb1 += wc0[e] * lb0[e];

      const float t3 = wc1[e] * lw1[e] * scale;
      const __hip_bfloat16 h3 = __float2bfloat16(t3);
      b1[4 + e] = *reinterpret_cast<const short*>(&h3);
      ws1 += __bfloat162float(h3);
      sb1 += wc1[e] * lb1[e];
    }
    acc0 = __builtin_amdgcn_mfma_f32_16x16x32_bf16(abf[kc], b0, acc0, 0, 0, 0);
    acc1 = __builtin_amdgcn_mfma_f32_16x16x32_bf16(abf[kc], b1, acc1, 0, 0, 0);
  }
  // each lane covered c with (c mod 32) in [q*8, q*8+8); reduce over q
  ws0 += __shfl_xor(ws0, 16); ws0 += __shfl_xor(ws0, 32);
  ws1 += __shfl_xor(ws1, 16); ws1 += __shfl_xor(ws1, 32);
  sb0 += __shfl_xor(sb0, 16); sb0 += __shfl_xor(sb0, 32);
  sb1 += __shfl_xor(sb1, 16); sb1 += __shfl_xor(sb1, 32);
  const float bia0 = isU ? wu_b[out0] : wv_b[out0 - 64];
  const float bia1 = isU ? wu_b[out1] : wv_b[out1 - 64];
  const float bb0 = scale * (bia0 + sb0);
  const float bb1 = scale * (bia1 + sb1);

  #pragma unroll
  for (int nt = 0; nt < 2; ++nt) {
    const int out  = nt ? out1 : out0;
    const floatx4 a = nt ? acc1 : acc0;
    const float ws = nt ? ws1 : ws0;
    const float bb = nt ? bb1 : bb0;
    #pragma unroll
    for (int r = 0; r < 4; ++r) {
      const int rowg = row0 + q * 4 + r;
      const float val = rs_r[r] * a[r] - mu_r[r] * rs_r[r] * ws + bb;
      if (out < 64) {
        U[(size_t)rowg * D_LOW + out] = val;
      } else {
        Vbf[(size_t)rowg * D_LOW + (out - 64)] = __float2bfloat16(val);
      }
    }
  }
}

// ---------------------------------------------------------------------------
// Kernel 2 (pair_fused): grid (N, 2B) x 256. Fuses the former tbin (target
// bins from x_true/pmask, ~30 VALU/lane prologue) and wprep (A-fragments
// from U[rowi] * wb_w, ~12 KB L2-resident reads) into the pair stage.
// Removes tbg (1.2 MB W+R) and wfragbuf (9.4 MB W + 18.9 MB R) + 2 launches.
// ---------------------------------------------------------------------------
__global__ __launch_bounds__(256) void pair_fused_kernel(
    const float* __restrict__ U, const __hip_bfloat16* __restrict__ Vbf,
    const float* __restrict__ wb_w, const float* __restrict__ wb_b,
    const float* __restrict__ x_true, const float* __restrict__ pmask,
    float* __restrict__ part, int N) {
  __shared__ float rbuf[8];
  const int i    = blockIdx.x;
  const int b    = blockIdx.y >> 1;
  const int half = blockIdx.y & 1;
  const int tid  = threadIdx.x;
  const int wave = tid >> 6, lane = tid & 63;
  const int q = lane >> 4, ln16 = lane & 15;
  const int rowi = b * N + i;
  const int jbase = half * 384 + wave * 96;
  const int q4 = q * 4;

  // ---- inline tbin: 6 (g,tt) slots per lane ----
  const float xi0 = x_true[rowi * 3 + 0];
  const float xi1 = x_true[rowi * 3 + 1];
  const float xi2 = x_true[rowi * 3 + 2];
  const float pmi = pmask[rowi];
  const float BW  = (22.0f - 2.0f) / 38.0f;
  int tbv_all[6];
  #pragma unroll
  for (int sl = 0; sl < 6; ++sl) {
    const int jr = jbase + (sl >> 1) * 32 + (sl & 1) * 16 + ln16;
    const int rowj = b * N + jr;
    const float dx = xi0 - x_true[rowj * 3 + 0];
    const float dy = xi1 - x_true[rowj * 3 + 1];
    const float dz = xi2 - x_true[rowj * 3 + 2];
    const float d  = sqrtf(dx * dx + dy * dy + dz * dz);
    int tb = (int)((d - 2.0f) / BW);
    tb = tb < 0 ? 0 : (tb > NBINS - 1 ? NBINS - 1 : tb);
    tbv_all[sl] = (pmi * pmask[rowj] > 0.f) ? tb : -1;
  }

  // ---- inline wfrag: bf16(U[rowi][c] * wb_w[n][c]) fragments ----
  const float* Up = U + (size_t)rowi * D_LOW;
  floatx4 u0[2], u1[2];
  #pragma unroll
  for (int s = 0; s < 2; ++s) {
    u0[s] = *reinterpret_cast<const floatx4*>(Up + s * 32 + q * 8);
    u1[s] = *reinterpret_cast<const floatx4*>(Up + s * 32 + q * 8 + 4);
  }
  short8 wfrag[3][2];
  #pragma unroll
  for (int t = 0; t < 3; ++t) {
    const int n = t * 16 + ln16;
    const bool valid = (n < NBINS);
    const float* wrow = wb_w + (size_t)(valid ? n : 0) * D_LOW;
    #pragma unroll
    for (int s = 0; s < 2; ++s) {
      const floatx4 w0 = *reinterpret_cast<const floatx4*>(wrow + s * 32 + q * 8);
      const floatx4 w1 = *reinterpret_cast<const floatx4*>(wrow + s * 32 + q * 8 + 4);
      short8 f;
      #pragma unroll
      for (int e = 0; e < 4; ++e) {
        const float v0 = valid ? u0[s][e] * w0[e] : 0.f;
        const float v1 = valid ? u1[s][e] * w1[e] : 0.f;
        const __hip_bfloat16 h0 = __float2bfloat16(v0);
        const __hip_bfloat16 h1 = __float2bfloat16(v1);
        f[e]     = *reinterpret_cast<const short*>(&h0);
        f[4 + e] = *reinterpret_cast<const short*>(&h1);
      }
      wfrag[t][s] = f;
    }
  }

  floatx4 bias_init[3];
  #pragma unroll
  for (int t = 0; t < 3; ++t)
    #pragma unroll
    for (int r = 0; r < 4; ++r) {
      const int bin = t * 16 + q * 4 + r;
      bias_init[t][r] = (bin < NBINS) ? LOG2E * wb_b[bin] : -INFINITY;
    }

  const short* Vp = reinterpret_cast<const short*>(Vbf) + (size_t)b * N * D_LOW;
  float ce_sum = 0.f, cnt_sum = 0.f;

  #pragma unroll
  for (int g = 0; g < 3; ++g) {
    short8 v[2][2];
    #pragma unroll
    for (int tt = 0; tt < 2; ++tt) {
      const size_t jr = jbase + g * 32 + tt * 16 + ln16;
      v[tt][0] = *reinterpret_cast<const short8*>(Vp + jr * D_LOW + q * 8);
      v[tt][1] = *reinterpret_cast<const short8*>(Vp + jr * D_LOW + 32 + q * 8);
    }

    floatx4 f[2][3];
    #pragma unroll
    for (int tt = 0; tt < 2; ++tt)
      #pragma unroll
      for (int t = 0; t < 3; ++t) {
        floatx4 a = bias_init[t];
        a = __builtin_amdgcn_mfma_f32_16x16x32_bf16(wfrag[t][0], v[tt][0], a, 0, 0, 0);
        a = __builtin_amdgcn_mfma_f32_16x16x32_bf16(wfrag[t][1], v[tt][1], a, 0, 0, 0);
        f[tt][t] = a;
      }

    #pragma unroll
    for (int tt = 0; tt < 2; ++tt) {
      const int tb  = tbv_all[g * 2 + tt];
      const int tbq = tb - q4;
      float s0 = 0.f, s1 = 0.f, s2 = 0.f, s3 = 0.f, lt = 0.f;
      #pragma unroll
      for (int t = 0; t < 3; ++t) {
        const floatx4 fv = f[tt][t];
        s0 += __builtin_amdgcn_exp2f(fv[0]);
        s1 += __builtin_amdgcn_exp2f(fv[1]);
        s2 += __builtin_amdgcn_exp2f(fv[2]);
        s3 += __builtin_amdgcn_exp2f(fv[3]);
        lt += (tbq == t * 16 + 0) ? fv[0] : 0.f;
        lt += (tbq == t * 16 + 1) ? fv[1] : 0.f;
        lt += (tbq == t * 16 + 2) ? fv[2] : 0.f;
        lt += (tbq == t * 16 + 3) ? fv[3] : 0.f;
      }
      float ssum = (s0 + s1) + (s2 + s3);
      ssum += __shfl_xor(ssum, 16); ssum += __shfl_xor(ssum, 32);
      const float ok = (tb >= 0) ? 1.f : 0.f;
      ce_sum  += ok * LN2 * (__builtin_amdgcn_logf(ssum) - 4.0f * lt);
      cnt_sum += ok;
    }
  }

  #pragma unroll
  for (int off = 32; off; off >>= 1) {
    ce_sum  += __shfl_xor(ce_sum, off);
    cnt_sum += __shfl_xor(cnt_sum, off);
  }
  if (lane == 0) { rbuf[wave] = ce_sum; rbuf[4 + wave] = cnt_sum; }
  __syncthreads();
  if (tid == 0) {
    const size_t slot = ((size_t)(b * 2 + half) * N + i) * 2;
    part[slot + 0] = rbuf[0] + rbuf[1] + rbuf[2] + rbuf[3];
    part[slot + 1] = rbuf[4] + rbuf[5] + rbuf[6] + rbuf[7];
  }
}

// ---------------------------------------------------------------------------
// Kernel 3: finalize — batch b owns 2N contiguous partial slots.
// ---------------------------------------------------------------------------
__global__ __launch_bounds__(256) void finalize_kernel(
    const float* __restrict__ part, float* __restrict__ out, int N, int B) {
  __shared__ float red[8];
  const int tid = threadIdx.x, wave = tid >> 6, lane = tid & 63;
  float loss = 0.f, vcount = 0.f;
  for (int b = 0; b < B; ++b) {
    float ce = 0.f, cnt = 0.f;
    for (int e = tid; e < 2 * N; e += 256) {
      const size_t base = ((size_t)b * 2 * N + e) * 2;
      ce  += part[base + 0];
      cnt += part[base + 1];
    }
    #pragma unroll
    for (int off = 32; off; off >>= 1) {
      ce  += __shfl_xor(ce, off);
      cnt += __shfl_xor(cnt, off);
    }
    if (lane == 0) { red[wave] = ce; red[4 + wave] = cnt; }
    __syncthreads();
    if (tid == 0) {
      const float s = red[0] + red[1] + red[2] + red[3];
      const float c = red[4] + red[5] + red[6] + red[7];
      if (c > 0.f) { loss += s / fmaxf(c, 1.f); vcount += 1.f; }
    }
    __syncthreads();
  }
  if (tid == 0) out[0] = (vcount > 0.f) ? loss / vcount : 0.f;
}

extern "C" void kernel_launch(void* const* d_in, const int* in_sizes, int n_in,
                              void* d_out, int out_size, void* d_ws, size_t ws_size,
                              hipStream_t stream) {
  const float* h_res  = (const float*)d_in[0];
  const float* x_true = (const float*)d_in[1];
  const float* pmask  = (const float*)d_in[2];
  const float* ln_w   = (const float*)d_in[3];
  const float* ln_b   = (const float*)d_in[4];
  const float* wu_w   = (const float*)d_in[5];
  const float* wu_b   = (const float*)d_in[6];
  const float* wv_w   = (const float*)d_in[7];
  const float* wv_b   = (const float*)d_in[8];
  const float* wb_w   = (const float*)d_in[9];
  const float* wb_b   = (const float*)d_in[10];

  const int B  = 2;
  const int N  = in_sizes[2] / B;
  const int BN = B * N;

  // ws: U f32[BN*64] | Vbf bf16[BN*64] | part f32[4*BN]
  float* U = (float*)d_ws;
  __hip_bfloat16* Vbf = (__hip_bfloat16*)(U + (size_t)BN * D_LOW);
  float* part = (float*)(Vbf + (size_t)BN * D_LOW);

  lnproj_fused_kernel<<<(BN / 16) * 4, 64, 0, stream>>>(
      h_res, ln_w, ln_b, wu_w, wu_b, wv_w, wv_b, U, Vbf, N);
  pair_fused_kernel<<<dim3(N, 2 * B), 256, 0, stream>>>(
      U, Vbf, wb_w, wb_b, x_true, pmask, part, N);
  finalize_kernel<<<1, 256, 0, stream>>>(part, (float*)d_out, N, B);
}

// Round 2
// 119.893 us; speedup vs baseline: 1.1150x; 1.1150x over previous
//
#include <hip/hip_runtime.h>
#include <hip/hip_bf16.h>
#include <math.h>

#define D_MODEL 512
#define D_LOW   64
#define NBINS   39
#define LOG2E   1.4426950408889634f
#define LN2     0.6931471805599453f
#define IT      2   // i-rows per pair block

typedef __attribute__((ext_vector_type(8))) short short8;
typedef __attribute__((ext_vector_type(4))) float floatx4;

// ---------------------------------------------------------------------------
// Kernel 0 (prep): fold LN affine + log2e into projection weights, ONCE.
//   w2bf[o][c] = bf16(w[o][c]*ln_w[c]*scale), w2sum[o] = sum_c (bf16-rounded),
//   b2[o] = scale*(b[o] + sum_c w[o][c]*ln_b[c]),  scale = log2e for U half.
// 128 blocks x 256. Tiny, high-parallelism — folding this into the 1-wave
// lnproj kernel (round 1) was a ~5x per-wave work multiplier; reverted.
// ---------------------------------------------------------------------------
__global__ __launch_bounds__(256) void prep_kernel(
    const float* __restrict__ ln_w, const float* __restrict__ ln_b,
    const float* __restrict__ wu_w, const float* __restrict__ wu_b,
    const float* __restrict__ wv_w, const float* __restrict__ wv_b,
    __hip_bfloat16* __restrict__ w2bf, float* __restrict__ w2sum,
    float* __restrict__ b2) {
  __shared__ float red[8];
  const int tid = threadIdx.x;
  const int o = blockIdx.x;
  const bool isU = (o < 64);
  const float* wrow = isU ? (wu_w + o * D_MODEL) : (wv_w + (o - 64) * D_MODEL);
  const float scale = isU ? LOG2E : 1.0f;

  float s1 = 0.f, s2 = 0.f;
  #pragma unroll
  for (int cc = 0; cc < 2; ++cc) {
    const int c = tid + cc * 256;
    const float w  = wrow[c];
    const float w2 = w * ln_w[c] * scale;
    const __hip_bfloat16 hb = __float2bfloat16(w2);
    w2bf[o * D_MODEL + c] = hb;
    s1 += __bfloat162float(hb);
    s2 += w * ln_b[c];
  }
  #pragma unroll
  for (int off = 32; off; off >>= 1) {
    s1 += __shfl_xor(s1, off);
    s2 += __shfl_xor(s2, off);
  }
  const int wave = tid >> 6, lane = tid & 63;
  if (lane == 0) { red[wave] = s1; red[4 + wave] = s2; }
  __syncthreads();
  if (tid == 0) {
    w2sum[o] = red[0] + red[1] + red[2] + red[3];
    const float ss2 = red[4] + red[5] + red[6] + red[7];
    b2[o] = scale * ((isU ? wu_b[o] : wv_b[o - 64]) + ss2);
  }
}

// ---------------------------------------------------------------------------
// Kernel 1 (lnproj): one wave per block, grid = (BN/16) * 8.
// Block = 16 rows x 16 outs (out-group og = blockIdx & 7). Reads pre-folded
// bf16 weights (1 short8 load + 1 MFMA per k-step), LN applied in epilogue.
// 8 og-groups (vs 4) halve per-wave work -> 768 waves, better latency cover.
// ---------------------------------------------------------------------------
__global__ __launch_bounds__(64) void lnproj_kernel(
    const float* __restrict__ h_res, const __hip_bfloat16* __restrict__ w2bf,
    const float* __restrict__ w2sum, const float* __restrict__ b2,
    float* __restrict__ U, __hip_bfloat16* __restrict__ Vbf, int N) {
  const int lane = threadIdx.x;
  const int q = lane >> 4, ln16 = lane & 15;
  const int rt = blockIdx.x >> 3, og = blockIdx.x & 7;
  const int row0 = rt * 16;
  const float* hp = h_res + (size_t)(row0 + ln16) * D_MODEL + q * 8;

  short8 abf[16];
  float sum = 0.f, ssq = 0.f;
  #pragma unroll
  for (int kc = 0; kc < 16; ++kc) {
    const floatx4 x0 = *reinterpret_cast<const floatx4*>(hp + kc * 32);
    const floatx4 x1 = *reinterpret_cast<const floatx4*>(hp + kc * 32 + 4);
    short8 a;
    #pragma unroll
    for (int e = 0; e < 4; ++e) {
      sum += x0[e]; ssq += x0[e] * x0[e];
      const __hip_bfloat16 hb = __float2bfloat16(x0[e]);
      a[e] = *reinterpret_cast<const short*>(&hb);
    }
    #pragma unroll
    for (int e = 0; e < 4; ++e) {
      sum += x1[e]; ssq += x1[e] * x1[e];
      const __hip_bfloat16 hb = __float2bfloat16(x1[e]);
      a[4 + e] = *reinterpret_cast<const short*>(&hb);
    }
    abf[kc] = a;
  }
  sum += __shfl_xor(sum, 16); sum += __shfl_xor(sum, 32);
  ssq += __shfl_xor(ssq, 16); ssq += __shfl_xor(ssq, 32);
  const float mu  = sum * (1.0f / (float)D_MODEL);
  const float var = ssq * (1.0f / (float)D_MODEL) - mu * mu;
  const float rs  = rsqrtf(var + 1e-5f);
  float mu_r[4], rs_r[4];
  #pragma unroll
  for (int r = 0; r < 4; ++r) {
    mu_r[r] = __shfl(mu, q * 4 + r);
    rs_r[r] = __shfl(rs, q * 4 + r);
  }

  const int out = og * 16 + ln16;            // 0..127
  const short* wp = reinterpret_cast<const short*>(w2bf);
  floatx4 acc = (floatx4){0.f, 0.f, 0.f, 0.f};
  #pragma unroll
  for (int kc = 0; kc < 16; ++kc) {
    const short8 bfr = *reinterpret_cast<const short8*>(
        wp + (size_t)out * D_MODEL + kc * 32 + q * 8);
    acc = __builtin_amdgcn_mfma_f32_16x16x32_bf16(abf[kc], bfr, acc, 0, 0, 0);
  }

  const float ws = w2sum[out];
  const float bb = b2[out];
  #pragma unroll
  for (int r = 0; r < 4; ++r) {
    const int rowg = row0 + q * 4 + r;
    const float val = rs_r[r] * acc[r] - mu_r[r] * rs_r[r] * ws + bb;
    if (out < 64) {
      U[(size_t)rowg * D_LOW + out] = val;
    } else {
      Vbf[(size_t)rowg * D_LOW + (out - 64)] = __float2bfloat16(val);
    }
  }
}

// ---------------------------------------------------------------------------
// Kernel 2 (pair): grid (N/IT, 2B) x 256. Each block handles IT=2 i-rows:
// the V tile loads (the latency bottleneck at IT=1: 90% stall, VALUBusy 44%,
// MfmaUtil 5.6%) are shared across both i, doubling the compute available to
// hide each load and halving total V traffic. x_true j-side loads and wb_w
// loads also shared across the 2 i. tbin + wfrag built inline (L2-resident).
// ---------------------------------------------------------------------------
__global__ __launch_bounds__(256) void pair_fused_kernel(
    const float* __restrict__ U, const __hip_bfloat16* __restrict__ Vbf,
    const float* __restrict__ wb_w, const float* __restrict__ wb_b,
    const float* __restrict__ x_true, const float* __restrict__ pmask,
    float* __restrict__ part, int N) {
  __shared__ float rbuf[8];
  const int b    = blockIdx.y >> 1;
  const int half = blockIdx.y & 1;
  const int i0   = blockIdx.x * IT;
  const int tid  = threadIdx.x;
  const int wave = tid >> 6, lane = tid & 63;
  const int q = lane >> 4, ln16 = lane & 15;
  const int jbase = half * 384 + wave * 96;
  const int q4 = q * 4;

  // ---- j-side coords (shared across it) ----
  float xj0[6], xj1[6], xj2[6], pmj[6];
  #pragma unroll
  for (int sl = 0; sl < 6; ++sl) {
    const int jr = jbase + (sl >> 1) * 32 + (sl & 1) * 16 + ln16;
    const int rowj = b * N + jr;
    xj0[sl] = x_true[rowj * 3 + 0];
    xj1[sl] = x_true[rowj * 3 + 1];
    xj2[sl] = x_true[rowj * 3 + 2];
    pmj[sl] = pmask[rowj];
  }
  const float BW = (22.0f - 2.0f) / 38.0f;
  int tbv[IT][6];
  #pragma unroll
  for (int it = 0; it < IT; ++it) {
    const int rowi = b * N + i0 + it;
    const float xi0 = x_true[rowi * 3 + 0];
    const float xi1 = x_true[rowi * 3 + 1];
    const float xi2 = x_true[rowi * 3 + 2];
    const float pmi = pmask[rowi];
    #pragma unroll
    for (int sl = 0; sl < 6; ++sl) {
      const float dx = xi0 - xj0[sl];
      const float dy = xi1 - xj1[sl];
      const float dz = xi2 - xj2[sl];
      const float d  = sqrtf(dx * dx + dy * dy + dz * dz);
      int tb = (int)((d - 2.0f) / BW);
      tb = tb < 0 ? 0 : (tb > NBINS - 1 ? NBINS - 1 : tb);
      tbv[it][sl] = (pmi * pmj[sl] > 0.f) ? tb : -1;
    }
  }

  // ---- inline wfrag: bf16(U[rowi][c] * wb_w[n][c]); wb_w shared across it --
  floatx4 u[IT][4];
  #pragma unroll
  for (int it = 0; it < IT; ++it) {
    const float* Up = U + (size_t)(b * N + i0 + it) * D_LOW;
    #pragma unroll
    for (int s = 0; s < 2; ++s) {
      u[it][s * 2 + 0] = *reinterpret_cast<const floatx4*>(Up + s * 32 + q * 8);
      u[it][s * 2 + 1] = *reinterpret_cast<const floatx4*>(Up + s * 32 + q * 8 + 4);
    }
  }
  short8 wfrag[IT][3][2];
  #pragma unroll
  for (int t = 0; t < 3; ++t) {
    const int n = t * 16 + ln16;
    const bool valid = (n < NBINS);
    const float* wrow = wb_w + (size_t)(valid ? n : 0) * D_LOW;
    #pragma unroll
    for (int s = 0; s < 2; ++s) {
      const floatx4 w0 = *reinterpret_cast<const floatx4*>(wrow + s * 32 + q * 8);
      const floatx4 w1 = *reinterpret_cast<const floatx4*>(wrow + s * 32 + q * 8 + 4);
      #pragma unroll
      for (int it = 0; it < IT; ++it) {
        short8 f;
        #pragma unroll
        for (int e = 0; e < 4; ++e) {
          const float v0 = valid ? u[it][s * 2 + 0][e] * w0[e] : 0.f;
          const float v1 = valid ? u[it][s * 2 + 1][e] * w1[e] : 0.f;
          const __hip_bfloat16 h0 = __float2bfloat16(v0);
          const __hip_bfloat16 h1 = __float2bfloat16(v1);
          f[e]     = *reinterpret_cast<const short*>(&h0);
          f[4 + e] = *reinterpret_cast<const short*>(&h1);
        }
        wfrag[it][t][s] = f;
      }
    }
  }

  floatx4 bias_init[3];
  #pragma unroll
  for (int t = 0; t < 3; ++t)
    #pragma unroll
    for (int r = 0; r < 4; ++r) {
      const int bin = t * 16 + q * 4 + r;
      bias_init[t][r] = (bin < NBINS) ? LOG2E * wb_b[bin] : -INFINITY;
    }

  const short* Vp = reinterpret_cast<const short*>(Vbf) + (size_t)b * N * D_LOW;
  float ce_sum = 0.f, cnt_sum = 0.f;

  short8 v[2][2];
  #pragma unroll
  for (int tt = 0; tt < 2; ++tt) {
    const size_t jr = jbase + tt * 16 + ln16;
    v[tt][0] = *reinterpret_cast<const short8*>(Vp + jr * D_LOW + q * 8);
    v[tt][1] = *reinterpret_cast<const short8*>(Vp + jr * D_LOW + 32 + q * 8);
  }

  #pragma unroll
  for (int g = 0; g < 3; ++g) {
    short8 vn[2][2];
    if (g < 2) {
      const int jb = jbase + (g + 1) * 32;
      #pragma unroll
      for (int tt = 0; tt < 2; ++tt) {
        const size_t jr = jb + tt * 16 + ln16;
        vn[tt][0] = *reinterpret_cast<const short8*>(Vp + jr * D_LOW + q * 8);
        vn[tt][1] = *reinterpret_cast<const short8*>(Vp + jr * D_LOW + 32 + q * 8);
      }
    }

    #pragma unroll
    for (int it = 0; it < IT; ++it) {
      floatx4 f[2][3];
      #pragma unroll
      for (int tt = 0; tt < 2; ++tt)
        #pragma unroll
        for (int t = 0; t < 3; ++t) {
          floatx4 a = bias_init[t];
          a = __builtin_amdgcn_mfma_f32_16x16x32_bf16(wfrag[it][t][0], v[tt][0], a, 0, 0, 0);
          a = __builtin_amdgcn_mfma_f32_16x16x32_bf16(wfrag[it][t][1], v[tt][1], a, 0, 0, 0);
          f[tt][t] = a;
        }

      #pragma unroll
      for (int tt = 0; tt < 2; ++tt) {
        const int tb  = tbv[it][g * 2 + tt];
        const int tbq = tb - q4;
        float s0 = 0.f, s1 = 0.f, s2 = 0.f, s3 = 0.f, lt = 0.f;
        #pragma unroll
        for (int t = 0; t < 3; ++t) {
          const floatx4 fv = f[tt][t];
          s0 += __builtin_amdgcn_exp2f(fv[0]);
          s1 += __builtin_amdgcn_exp2f(fv[1]);
          s2 += __builtin_amdgcn_exp2f(fv[2]);
          s3 += __builtin_amdgcn_exp2f(fv[3]);
          lt += (tbq == t * 16 + 0) ? fv[0] : 0.f;
          lt += (tbq == t * 16 + 1) ? fv[1] : 0.f;
          lt += (tbq == t * 16 + 2) ? fv[2] : 0.f;
          lt += (tbq == t * 16 + 3) ? fv[3] : 0.f;
        }
        float ssum = (s0 + s1) + (s2 + s3);
        ssum += __shfl_xor(ssum, 16); ssum += __shfl_xor(ssum, 32);
        const float ok = (tb >= 0) ? 1.f : 0.f;
        ce_sum  += ok * LN2 * (__builtin_amdgcn_logf(ssum) - 4.0f * lt);
        cnt_sum += ok;
      }
    }

    if (g < 2) {
      #pragma unroll
      for (int tt = 0; tt < 2; ++tt) {
        v[tt][0] = vn[tt][0]; v[tt][1] = vn[tt][1];
      }
    }
  }

  #pragma unroll
  for (int off = 32; off; off >>= 1) {
    ce_sum  += __shfl_xor(ce_sum, off);
    cnt_sum += __shfl_xor(cnt_sum, off);
  }
  if (lane == 0) { rbuf[wave] = ce_sum; rbuf[4 + wave] = cnt_sum; }
  __syncthreads();
  if (tid == 0) {
    const size_t slot = ((size_t)blockIdx.y * gridDim.x + blockIdx.x) * 2;
    part[slot + 0] = rbuf[0] + rbuf[1] + rbuf[2] + rbuf[3];
    part[slot + 1] = rbuf[4] + rbuf[5] + rbuf[6] + rbuf[7];
  }
}

// ---------------------------------------------------------------------------
// Kernel 3: finalize — batch b owns slots [2b*NP, (2b+2)*NP), NP = N/IT.
// ---------------------------------------------------------------------------
__global__ __launch_bounds__(256) void finalize_kernel(
    const float* __restrict__ part, float* __restrict__ out, int NP, int B) {
  __shared__ float red[8];
  const int tid = threadIdx.x, wave = tid >> 6, lane = tid & 63;
  float loss = 0.f, vcount = 0.f;
  for (int b = 0; b < B; ++b) {
    float ce = 0.f, cnt = 0.f;
    for (int e = tid; e < 2 * NP; e += 256) {
      const size_t base = ((size_t)b * 2 * NP + e) * 2;
      ce  += part[base + 0];
      cnt += part[base + 1];
    }
    #pragma unroll
    for (int off = 32; off; off >>= 1) {
      ce  += __shfl_xor(ce, off);
      cnt += __shfl_xor(cnt, off);
    }
    if (lane == 0) { red[wave] = ce; red[4 + wave] = cnt; }
    __syncthreads();
    if (tid == 0) {
      const float s = red[0] + red[1] + red[2] + red[3];
      const float c = red[4] + red[5] + red[6] + red[7];
      if (c > 0.f) { loss += s / fmaxf(c, 1.f); vcount += 1.f; }
    }
    __syncthreads();
  }
  if (tid == 0) out[0] = (vcount > 0.f) ? loss / vcount : 0.f;
}

extern "C" void kernel_launch(void* const* d_in, const int* in_sizes, int n_in,
                              void* d_out, int out_size, void* d_ws, size_t ws_size,
                              hipStream_t stream) {
  const float* h_res  = (const float*)d_in[0];
  const float* x_true = (const float*)d_in[1];
  const float* pmask  = (const float*)d_in[2];
  const float* ln_w   = (const float*)d_in[3];
  const float* ln_b   = (const float*)d_in[4];
  const float* wu_w   = (const float*)d_in[5];
  const float* wu_b   = (const float*)d_in[6];
  const float* wv_w   = (const float*)d_in[7];
  const float* wv_b   = (const float*)d_in[8];
  const float* wb_w   = (const float*)d_in[9];
  const float* wb_b   = (const float*)d_in[10];

  const int B  = 2;
  const int N  = in_sizes[2] / B;
  const int BN = B * N;
  const int NP = N / IT;

  // ws: U f32[BN*64] | Vbf bf16[BN*64] | part f32[2B*NP*2]
  //     | w2bf bf16[128*512] | w2sum f32[128] | b2 f32[128]
  float* U = (float*)d_ws;
  __hip_bfloat16* Vbf = (__hip_bfloat16*)(U + (size_t)BN * D_LOW);
  float* part = (float*)(Vbf + (size_t)BN * D_LOW);
  __hip_bfloat16* w2bf = (__hip_bfloat16*)(part + (size_t)2 * B * NP * 2);
  float* w2sum = (float*)(w2bf + 128 * D_MODEL);
  float* b2    = w2sum + 128;

  prep_kernel<<<128, 256, 0, stream>>>(ln_w, ln_b, wu_w, wu_b, wv_w, wv_b,
                                       w2bf, w2sum, b2);
  lnproj_kernel<<<(BN / 16) * 8, 64, 0, stream>>>(h_res, w2bf, w2sum, b2,
                                                  U, Vbf, N);
  pair_fused_kernel<<<dim3(NP, 2 * B), 256, 0, stream>>>(
      U, Vbf, wb_w, wb_b, x_true, pmask, part, N);
  finalize_kernel<<<1, 256, 0, stream>>>(part, (float*)d_out, NP, B);
}